// Round 4
// baseline (459.023 us; speedup 1.0000x reference)
//
#include <hip/hip_runtime.h>
#include <stdint.h>

#define DI __device__ __forceinline__

typedef __attribute__((ext_vector_type(4))) float f4;
typedef __attribute__((ext_vector_type(2))) float f2;
typedef __attribute__((ext_vector_type(4))) float f32x4;
typedef _Float16 f16;
typedef __attribute__((ext_vector_type(8))) f16 f16x8;

static constexpr int BATCH = 16, C = 256, H = 96, W = 96, QK = 64, F = 384;
static constexpr int P = H * W;  // 9216

// ---- workspace layout (bytes) ----
static constexpr size_t OFF_WC = 0;                                    // 384*256*2
static constexpr size_t OFF_BC = OFF_WC + (size_t)F * C * 2;
static constexpr size_t OFF_QP = OFF_BC + 4096;
static constexpr size_t OFF_KP = OFF_QP + (size_t)BATCH * P * QK * 2;  // 18.9 MB each
static constexpr size_t OFF_VP = OFF_KP + (size_t)BATCH * P * QK * 2;
static constexpr size_t OFF_O1 = OFF_VP + (size_t)BATCH * P * C * 2;   // 75.5 MB
static constexpr size_t WS_END = OFF_O1 + (size_t)BATCH * P * C * 2;   // ~189 MB

DI void gll16(const void* g, void* l) {
  __builtin_amdgcn_global_load_lds((const __attribute__((address_space(1))) void*)g,
                                   (__attribute__((address_space(3))) void*)l, 16, 0, 0);
}
DI f32x4 mfma16(f16x8 a, f16x8 b, f32x4 c) {
  return __builtin_amdgcn_mfma_f32_16x16x32_f16(a, b, c, 0, 0, 0);
}
DI int mod13(int v) {  // valid for 0..6553
  return v - 13 * ((v * 5042) >> 16);
}

// ---------------- kernel 1: weights -> fp16 [f][c], bias concat ----------------
__global__ __launch_bounds__(256) void wprep_kernel(
    const float* __restrict__ Wq, const float* __restrict__ bq,
    const float* __restrict__ Wk, const float* __restrict__ bk,
    const float* __restrict__ Wv, const float* __restrict__ bv,
    f16* __restrict__ Wc, float* __restrict__ bc) {
  const int f = blockIdx.x, t = threadIdx.x;
  const float* src; int row;
  if (f < 64)       { src = Wq; row = f; }
  else if (f < 128) { src = Wk; row = f - 64; }
  else              { src = Wv; row = f - 128; }
  Wc[f * C + t] = (f16)src[row * C + t];
  if (t == 0) bc[f] = (f < 64) ? bq[f] : (f < 128) ? bk[f - 64] : bv[f - 128];
}

// ---------------- kernel 2: QKV GEMM, fused transpose, B direct-to-reg ----------------
// out[p][f] = sum_c x[b][c][p] * Wc[f][c] + bias.  M=9216, N=384, K=256.
// A: fp32 x -> regs (dwordx2) -> fp16 LDS [128][64], 16B blocks XOR-swizzled (blk ^ (p&7)).
// B: fragments straight from global (L2-resident 196KB) into registers, no LDS.
__global__ __launch_bounds__(256, 3) void gemm_qkv(
    const float* __restrict__ x, const f16* __restrict__ Wc, const float* __restrict__ bc,
    f16* __restrict__ Qp, f16* __restrict__ Kp, f16* __restrict__ Vp) {
  __shared__ f16 As[2][128 * 64];  // 16 KB x2
  const int tid = threadIdx.x, lane = tid & 63, wv = tid >> 6;
  const int wm = wv >> 1, wn = wv & 1;
  // XCD-chunked swizzle: 3456 = 8 XCD x 432; consecutive chunks share (b,mt) A-slab.
  const int c2 = ((blockIdx.x & 7) * 432) + (blockIdx.x >> 3);
  const int b = c2 / 216, r = c2 % 216;
  const int mt = r / 3, nt = r % 3;
  const int m0 = mt * 128, f0 = nt * 128;
  const float* Ax = x + (size_t)b * C * P + m0;

  const int pp = (tid & 63) * 2;  // p-pair base (consecutive lanes -> consecutive pairs)
  const int cq = tid >> 6;        // c-16-group (one per wave)

  f32x4 acc[4][4];
#pragma unroll
  for (int i = 0; i < 4; ++i)
#pragma unroll
    for (int j = 0; j < 4; ++j) acc[i][j] = (f32x4){0.f, 0.f, 0.f, 0.f};

  f2 av[16];       // 16 channels x p-pair
  f16x8 breg[2][4];

  auto loadA = [&](int k0) {
#pragma unroll
    for (int u = 0; u < 16; ++u)
      av[u] = *reinterpret_cast<const f2*>(Ax + (size_t)(k0 + cq * 16 + u) * P + pp);
  };
  auto writeA = [&](int bsel) {
#pragma unroll
    for (int rr = 0; rr < 2; ++rr) {
      const int p = pp + rr;
#pragma unroll
      for (int ob = 0; ob < 2; ++ob) {
        const int cb = cq * 2 + ob;
        f16x8 hv;
#pragma unroll
        for (int u = 0; u < 8; ++u) hv[u] = (f16)av[ob * 8 + u][rr];
        *reinterpret_cast<f16x8*>(&As[bsel][p * 64 + ((cb ^ (p & 7)) << 3)]) = hv;
      }
    }
  };
  auto loadB = [&](int k0) {
#pragma unroll
    for (int ks = 0; ks < 2; ++ks) {
      const int kb = ks * 4 + (lane >> 4);
#pragma unroll
      for (int j = 0; j < 4; ++j) {
        const int row = f0 + wn * 64 + j * 16 + (lane & 15);
        breg[ks][j] = *reinterpret_cast<const f16x8*>(&Wc[(size_t)row * C + k0 + kb * 8]);
      }
    }
  };
  auto compute = [&](int bsel) {
#pragma unroll
    for (int ks = 0; ks < 2; ++ks) {
      const int kb = ks * 4 + (lane >> 4);
      f16x8 a[4];
#pragma unroll
      for (int i = 0; i < 4; ++i) {
        const int row = wm * 64 + i * 16 + (lane & 15);
        a[i] = *reinterpret_cast<const f16x8*>(&As[bsel][row * 64 + ((kb ^ (row & 7)) << 3)]);
      }
#pragma unroll
      for (int i = 0; i < 4; ++i)
#pragma unroll
        for (int j = 0; j < 4; ++j) acc[i][j] = mfma16(a[i], breg[ks][j], acc[i][j]);
    }
  };

  loadA(0);
  writeA(0);
  __syncthreads();
  int buf = 0;
#pragma unroll
  for (int t = 0; t < 3; ++t) {
    loadB(t * 64);           // B frags from L2 (used by compute below)
    loadA((t + 1) * 64);     // next A tile in flight during compute
    compute(buf);
    writeA(buf ^ 1);         // waits on av arrival after MFMA issue
    __syncthreads();
    buf ^= 1;
  }
  loadB(192);
  compute(buf);

  // epilogue: add bias, fp16 stores
#pragma unroll
  for (int j = 0; j < 4; ++j) {
    const int fl = wn * 64 + j * 16 + (lane & 15);
    const float bias = bc[f0 + fl];
#pragma unroll
    for (int i = 0; i < 4; ++i) {
#pragma unroll
      for (int q = 0; q < 4; ++q) {
        const int p = m0 + wm * 64 + i * 16 + ((lane >> 4) << 2) + q;
        const float v = acc[i][j][q] + bias;
        if (nt == 0) {
          if (fl < 64) Qp[((size_t)b * P + p) * QK + fl] = (f16)v;
          else         Kp[((size_t)b * P + p) * QK + (fl - 64)] = (f16)v;
        } else {
          Vp[((size_t)b * P + p) * C + (nt - 1) * 128 + fl] = (f16)v;
        }
      }
    }
  }
}

// ---------------- kernel 3: column attention, one block per (b,w), 2 blocks/CU ----------------
// LDS 77.5 KB: qs[96][64] | ks[96][64] (sP[96][128] overlays both) | vt[256][104] rot13 | red[2x2][96]
__global__ __launch_bounds__(256, 2) void attn_kernel(
    const f16* __restrict__ Qp, const f16* __restrict__ Kp, const f16* __restrict__ Vp,
    f16* __restrict__ O1) {
  __shared__ char smem[24576 + 53248 + 768 + 768];
  f16*   qs   = (f16*)smem;                    // [96][64] xor-swz rows
  f16*   ksm  = (f16*)(smem + 12288);
  f16*   sP   = (f16*)smem;                    // overlays qs+ks after scores
  f16*   vt   = (f16*)(smem + 24576);          // [256][104] mod-13 rotated 16B blocks
  float* redm = (float*)(smem + 24576 + 53248);  // [2][96] cross-wave max
  float* reds = redm + 192;                      // [2][96] cross-wave sum

  const int tid = threadIdx.x, lane = tid & 63, wv = tid >> 6;
  const int wmq = wv >> 1, wnq = wv & 1;
  const int id = ((blockIdx.x & 7) * 192) + (blockIdx.x >> 3);  // XCD-chunked
  const int b = id / 96, w = id % 96;

  // ---- phase 0: V column loads (reg transpose) + Q/K global_load_lds ----
  const int cc = tid;
  f16 vv[96];
#pragma unroll
  for (int g = 0; g < 96; ++g)
    vv[g] = Vp[((size_t)b * P + g * 96 + w) * C + cc];

  {
    const int grow = lane >> 3;
    const int lblk = (lane & 7) ^ grow;
#pragma unroll
    for (int s = 0; s < 3; ++s) {
      const int sec = wv * 3 + s;
      const int row = sec * 8 + grow;
      const size_t src = ((size_t)b * P + (size_t)row * 96 + w) * QK + lblk * 8;
      gll16(Qp + src, &qs[sec * 512]);
      gll16(Kp + src, &ksm[sec * 512]);
    }
  }
  {
    const int r13 = mod13(cc);
#pragma unroll
    for (int ob = 0; ob < 12; ++ob) {
      int phys = ob + r13;
      if (phys >= 13) phys -= 13;
      f16x8 pk;
#pragma unroll
      for (int e = 0; e < 8; ++e) pk[e] = vv[ob * 8 + e];
      *reinterpret_cast<f16x8*>(&vt[cc * 104 + phys * 8]) = pk;
    }
  }
  __syncthreads();

  // ---- scores in registers: S[h][g] = sum_q Q[h][q] K[g][q] ----
  f32x4 acc[3][3];
#pragma unroll
  for (int i = 0; i < 3; ++i)
#pragma unroll
    for (int j = 0; j < 3; ++j) acc[i][j] = (f32x4){0.f, 0.f, 0.f, 0.f};
#pragma unroll
  for (int ks = 0; ks < 2; ++ks) {
    const int kb = ks * 4 + (lane >> 4);
    f16x8 a[3], bb[3];
#pragma unroll
    for (int i = 0; i < 3; ++i) {
      const int row = wmq * 48 + i * 16 + (lane & 15);
      a[i] = *reinterpret_cast<const f16x8*>(&qs[row * 64 + ((kb ^ (row & 7)) << 3)]);
    }
#pragma unroll
    for (int j = 0; j < 3; ++j) {
      const int row = wnq * 48 + j * 16 + (lane & 15);
      bb[j] = *reinterpret_cast<const f16x8*>(&ksm[row * 64 + ((kb ^ (row & 7)) << 3)]);
    }
#pragma unroll
    for (int i = 0; i < 3; ++i)
#pragma unroll
      for (int j = 0; j < 3; ++j) acc[i][j] = mfma16(a[i], bb[j], acc[i][j]);
  }

  // ---- register softmax ----
#pragma unroll
  for (int i = 0; i < 3; ++i)
#pragma unroll
    for (int q = 0; q < 4; ++q) {
      float m = fmaxf(fmaxf(acc[i][0][q], acc[i][1][q]), acc[i][2][q]);
#pragma unroll
      for (int o = 8; o >= 1; o >>= 1) m = fmaxf(m, __shfl_xor(m, o, 64));
      if ((lane & 15) == 0)
        redm[wnq * 96 + wmq * 48 + i * 16 + ((lane >> 4) << 2) + q] = m;
    }
  __syncthreads();  // also frees qs/ks for sP overlay
#pragma unroll
  for (int i = 0; i < 3; ++i)
#pragma unroll
    for (int q = 0; q < 4; ++q) {
      const int h = wmq * 48 + i * 16 + ((lane >> 4) << 2) + q;
      const float m = fmaxf(redm[h], redm[96 + h]);
      float s = 0.f;
#pragma unroll
      for (int j = 0; j < 3; ++j) {
        const float p = __expf(acc[i][j][q] - m);
        acc[i][j][q] = p;
        s += p;
      }
#pragma unroll
      for (int o = 8; o >= 1; o >>= 1) s += __shfl_xor(s, o, 64);
      if ((lane & 15) == 0) reds[wnq * 96 + h] = s;
    }
  // unnormalized P -> sP fp16 (xor-swizzled rows)
#pragma unroll
  for (int i = 0; i < 3; ++i)
#pragma unroll
    for (int q = 0; q < 4; ++q) {
      const int h = wmq * 48 + i * 16 + ((lane >> 4) << 2) + q;
#pragma unroll
      for (int j = 0; j < 3; ++j) {
        const int g = wnq * 48 + j * 16 + (lane & 15);
        sP[h * 128 + (((g >> 3) ^ (h & 7)) << 3) + (g & 7)] = (f16)acc[i][j][q];
      }
    }
  __syncthreads();

  // ---- PV: out[h][c] = sum_g P[h][g] vt[c][g]; deferred 1/sum ----
  {
    f32x4 o[3][8];
#pragma unroll
    for (int i = 0; i < 3; ++i)
#pragma unroll
      for (int j = 0; j < 8; ++j) o[i][j] = (f32x4){0.f, 0.f, 0.f, 0.f};
#pragma unroll
    for (int ks = 0; ks < 3; ++ks) {
      const int gb = ks * 4 + (lane >> 4);
      f16x8 a[3];
#pragma unroll
      for (int i = 0; i < 3; ++i) {
        const int row = wmq * 48 + i * 16 + (lane & 15);
        a[i] = *reinterpret_cast<const f16x8*>(&sP[row * 128 + ((gb ^ (row & 7)) << 3)]);
      }
#pragma unroll
      for (int j = 0; j < 8; ++j) {
        const int crow = wnq * 128 + j * 16 + (lane & 15);
        int phys = gb + mod13(crow);
        if (phys >= 13) phys -= 13;
        const f16x8 bv = *reinterpret_cast<const f16x8*>(&vt[crow * 104 + phys * 8]);
#pragma unroll
        for (int i = 0; i < 3; ++i) o[i][j] = mfma16(a[i], bv, o[i][j]);
      }
    }
    f16* ob_ = O1 + ((size_t)b * 96 + w) * 96 * C;
#pragma unroll
    for (int i = 0; i < 3; ++i) {
#pragma unroll
      for (int q = 0; q < 4; ++q) {
        const int h = wmq * 48 + i * 16 + ((lane >> 4) << 2) + q;
        const float rs = 1.0f / (reds[h] + reds[96 + h]);
#pragma unroll
        for (int j = 0; j < 8; ++j) {
          const int c = wnq * 128 + j * 16 + (lane & 15);
          ob_[(size_t)h * C + c] = (f16)(o[i][j][q] * rs);
        }
      }
    }
  }
}

// ---------------- kernel 4: epilogue transpose + gamma*out + x ----------------
__global__ __launch_bounds__(256, 3) void epi_kernel(
    const f16* __restrict__ O1, const float* __restrict__ x,
    const float* __restrict__ gamma, float* __restrict__ out) {
  __shared__ f16 t[96 * 256];  // [w][c], 16B blocks swizzled: phys = blk ^ (w&31)
  const int id = ((blockIdx.x & 7) * 192) + (blockIdx.x >> 3);
  const int b = id / 96, h = id % 96;
  const int tid = threadIdx.x, lane = tid & 63, wv = tid >> 6;
  {
    const int grow = lane >> 5;
#pragma unroll
    for (int s = 0; s < 12; ++s) {
      const int sec = wv * 12 + s;
      const int row = sec * 2 + grow;
      const int lblk = (lane & 31) ^ (row & 31);
      gll16(O1 + (((size_t)b * 96 + row) * 96 + h) * C + lblk * 8, &t[sec * 512]);
    }
  }
  __syncthreads();
  const float g = gamma[0];
#pragma unroll
  for (int pass = 0; pass < 24; ++pass) {
    const int idx = pass * 256 + tid;
    const int c = idx / 24, wc = idx % 24;
    const int w4 = wc * 4;
    const size_t o = (((size_t)b * C + c) * H + h) * W + w4;
    const f4 xv = *reinterpret_cast<const f4*>(x + o);
    f4 r;
#pragma unroll
    for (int u = 0; u < 4; ++u) {
      const int wr = w4 + u;
      const f16 hv = t[wr * 256 + (((c >> 3) ^ (wr & 31)) << 3) + (c & 7)];
      r[u] = g * (float)hv + xv[u];
    }
    *reinterpret_cast<f4*>(out + o) = r;
  }
}

extern "C" void kernel_launch(void* const* d_in, const int* in_sizes, int n_in,
                              void* d_out, int out_size, void* d_ws, size_t ws_size,
                              hipStream_t stream) {
  const float* x     = (const float*)d_in[0];
  const float* Wq    = (const float*)d_in[1];
  const float* bq    = (const float*)d_in[2];
  const float* Wk    = (const float*)d_in[3];
  const float* bk    = (const float*)d_in[4];
  const float* Wv    = (const float*)d_in[5];
  const float* bv    = (const float*)d_in[6];
  const float* gamma = (const float*)d_in[7];
  float* out = (float*)d_out;
  char* ws = (char*)d_ws;
  if (ws_size < WS_END) return;

  f16*   Wc = (f16*)(ws + OFF_WC);
  float* bc = (float*)(ws + OFF_BC);
  f16*   Qp = (f16*)(ws + OFF_QP);
  f16*   Kp = (f16*)(ws + OFF_KP);
  f16*   Vp = (f16*)(ws + OFF_VP);
  f16*   O1 = (f16*)(ws + OFF_O1);

  wprep_kernel<<<dim3(F), dim3(256), 0, stream>>>(Wq, bq, Wk, bk, Wv, bv, Wc, bc);
  gemm_qkv<<<dim3(3456), dim3(256), 0, stream>>>(x, Wc, bc, Qp, Kp, Vp);
  attn_kernel<<<dim3(BATCH * 96), dim3(256), 0, stream>>>(Qp, Kp, Vp, O1);
  epi_kernel<<<dim3(BATCH * 96), dim3(256), 0, stream>>>(O1, x, gamma, out);
}